// Round 18
// baseline (41.474 us; speedup 1.0000x reference)
//
#include <hip/hip_runtime.h>
#include <stdint.h>

typedef __attribute__((ext_vector_type(4)))  int   i32x4;
typedef __attribute__((ext_vector_type(8)))  int   i32x8;
typedef __attribute__((ext_vector_type(16))) float f32x16;

#define NROWS 4096
#define RB    512      // bytes per fp4 row (1024 elems * 0.5B)
#define NKT   16       // K-tiles of 32 bytes (64 elements)
#define NP    64       // 64-row panels
#define NBLK  2080     // NP*(NP+1)/2 triangular 64x64 tiles
#define COS_EPS 1e-8f
#define SCL   0x7F7F7F7F   // E8M0 = 127 -> scale 1.0
#define FP4   4            // f8f6f4 format code E2M1

__device__ __forceinline__ void gload16(const uint8_t* g, uint8_t* l) {
  __builtin_amdgcn_global_load_lds(
      (const __attribute__((address_space(1))) uint32_t*)g,
      (__attribute__((address_space(3))) uint32_t*)l, 16, 0, 0);
}

__device__ __forceinline__ i32x8 ext8(i32x4 lo) {
  i32x8 r;
  r[0] = lo[0]; r[1] = lo[1]; r[2] = lo[2]; r[3] = lo[3];
  r[4] = 0; r[5] = 0; r[6] = 0; r[7] = 0;
  return r;
}

// nearest e2m1 code for |x| (codes 0..7 -> {0,.5,1,1.5,2,3,4,6})
__device__ __forceinline__ uint32_t fp4q(float x) {
  const float a = fabsf(x);
  uint32_t c;
  if      (a < 0.25f) c = 0;
  else if (a < 0.75f) c = 1;
  else if (a < 1.25f) c = 2;
  else if (a < 1.75f) c = 3;
  else if (a < 2.5f)  c = 4;
  else if (a < 3.5f)  c = 5;
  else if (a < 5.0f)  c = 6;
  else                c = 7;
  return c | (x < 0.f ? 8u : 0u);
}

// ---------------- prep: sq, 1/norm, fp4 e2m1 copy ----------------
extern "C" __global__ void __launch_bounds__(256) prep_kernel(
    const float* __restrict__ F, uint8_t* __restrict__ Fb,
    float* __restrict__ sq, float* __restrict__ rn) {
  const int row  = blockIdx.x * 4 + (threadIdx.x >> 6);
  const int lane = threadIdx.x & 63;
  const float4* src = (const float4*)(F + (size_t)row * 1024 + lane * 16);
  float4 v[4];
#pragma unroll
  for (int i = 0; i < 4; ++i) v[i] = src[i];
  float s = 0.f;
#pragma unroll
  for (int i = 0; i < 4; ++i)
    s += v[i].x * v[i].x + v[i].y * v[i].y + v[i].z * v[i].z + v[i].w * v[i].w;
  uint32_t b[2] = {0, 0};
#pragma unroll
  for (int i = 0; i < 4; ++i) {
    const uint32_t n0 = fp4q(v[i].x), n1 = fp4q(v[i].y);
    const uint32_t n2 = fp4q(v[i].z), n3 = fp4q(v[i].w);
    const uint32_t byte2 = (n0 | (n1 << 4)) | ((n2 | (n3 << 4)) << 8);
    b[i >> 1] |= byte2 << ((i & 1) * 16);
  }
  *(uint2*)(Fb + (size_t)row * RB + lane * 8) = make_uint2(b[0], b[1]);
#pragma unroll
  for (int off = 32; off; off >>= 1) s += __shfl_down(s, off);
  if (lane == 0) {
    sq[row] = s;
    rn[row] = 1.0f / fmaxf(sqrtf(s), COS_EPS);
  }
}

// ---------------- fused gram: FP4, triangular 64x64 tiles, high residency --
// 2080 blocks (8.1/CU, ~6 resident), 4 waves (2x2), wave = one 32x32x64 fp4
// MFMA per K-tile. 3-slot LDS ring (3 x 4 KB = 12 KB/block). Per K-tile:
// {2 ds_read_b128 | 1 gload_lds (stage kt+2) | 1 MFMA setprio | vmcnt(1) |
// barrier}. Frag-major LDS: frag = contiguous 1 KB wave read, 0 conflicts.
// A-frag f granule l at f*1024 + l*16; B at +2048.
extern "C" __global__ void __launch_bounds__(256, 6) gram_kernel(
    const uint8_t* __restrict__ Fb, const float* __restrict__ sq,
    const float* __restrict__ rn, const int* __restrict__ y,
    float* __restrict__ partials) {
  __shared__ __align__(16) uint8_t lds[3][4096];   // [slot][A 2KB | B 2KB]
  __shared__ float wsum[4];

  // XCD-chunked bijection (2080 = 8*260) + triangular staircase decode
  int sid = (int)(blockIdx.x & 7) * 260 + (int)(blockIdx.x >> 3);
  int ti = 0, rem = sid;
  while (rem >= NP - ti) { rem -= NP - ti; ++ti; }
  const int tj = ti + rem;
  const bool diag = (ti == tj);

  const int tid  = threadIdx.x;
  const int lane = tid & 63;
  const int wid  = tid >> 6;
  const int wr   = wid >> 1;      // 0..1 : 32-row group
  const int wc   = wid & 1;       // 0..1 : 32-col group
  const int kg   = lane >> 5;
  const int r32  = lane & 31;

  // staging: thread stages ONE 16B granule per K-tile.
  // tid<128 -> A frag f=tid>>6, lane l=tid&63; tid>=128 -> B likewise.
  const int t2 = tid & 127;
  const int sf = t2 >> 6, sl = t2 & 63;
  const int srow = sf * 32 + (sl & 31);
  const int scol = (sl >> 5) * 16;
  const uint8_t* gsrc = Fb +
      (size_t)(((tid < 128) ? ti : tj) * 64 + srow) * RB + scol;
  uint8_t* ldsT = &lds[0][0] + tid * 16;

  // fragment read offsets (frag-major): A wr -> wr*1024; B wc -> 2048+wc*1024
  const int offA = wr * 1024 + lane * 16;
  const int offB = 2048 + wc * 1024 + lane * 16;

  f32x16 acc = {};

#define STAGE(kt2) gload16(gsrc + (kt2) * 32, ldsT + ((kt2) % 3) * 4096)

  // prologue: K-tiles 0,1 in flight; wait tile 0; publish
  STAGE(0); STAGE(1);
  asm volatile("s_waitcnt vmcnt(1)");
  __builtin_amdgcn_s_barrier();
  __builtin_amdgcn_sched_barrier(0);

#pragma unroll 1
  for (int kt = 0; kt < NKT; ++kt) {
    const uint8_t* slp = &lds[0][0] + (kt % 3) * 4096;
    const i32x8 A = ext8(*(const i32x4*)(slp + offA));
    const i32x8 B = ext8(*(const i32x4*)(slp + offB));

    if (kt + 2 < NKT) STAGE(kt + 2);

    __builtin_amdgcn_s_setprio(1);
    acc = __builtin_amdgcn_mfma_scale_f32_32x32x64_f8f6f4(
        A, B, acc, FP4, FP4, 0, SCL, 0, SCL);
    __builtin_amdgcn_s_setprio(0);

    if (kt + 2 < NKT)       asm volatile("s_waitcnt vmcnt(1)");  // kt+1 landed
    else if (kt == NKT - 2) asm volatile("s_waitcnt vmcnt(0)");
    if (kt < NKT - 1) {
      __builtin_amdgcn_s_barrier();
      __builtin_amdgcn_sched_barrier(0);   // next-iter ds_reads stay below
    }
  }

#undef STAGE

  // ---------- epilogue: triangle weights (32x32 C/D: col=r32, row=(e&3)+8*(e>>2)+4*kg)
  const int gj = tj * 64 + wc * 32 + r32;
  const float sqj = sq[gj], rnj = rn[gj];
  const int yj = y[gj];
  float lsum = 0.f;
#pragma unroll
  for (int e = 0; e < 16; ++e) {
    const int gi = ti * 64 + wr * 32 + (e & 3) + 8 * (e >> 2) + 4 * kg;
    const float g  = acc[e];
    const float d2 = sq[gi] + sqj - 2.0f * g;
    const float dist = d2 > 0.f ? sqrtf(d2) : 0.f;
    const float sim  = g * rn[gi] * rnj;
    const float sgn  = (y[gi] == yj) ? 1.0f : -1.0f;
    float wgt;
    if (diag) wgt = (gj > gi) ? 2.0f : ((gj == gi) ? 1.0f : 0.0f);
    else      wgt = 2.0f;
    lsum += wgt * sgn * (dist - sim);
  }
#pragma unroll
  for (int off = 32; off; off >>= 1) lsum += __shfl_down(lsum, off);
  if (lane == 0) wsum[wid] = lsum;
  __syncthreads();
  if (tid == 0)
    partials[blockIdx.x] = wsum[0] + wsum[1] + wsum[2] + wsum[3];
}

// ---------------- deterministic final reduce ----------------
extern "C" __global__ void __launch_bounds__(256) reduce_kernel(
    const float* __restrict__ partials, float* __restrict__ out) {
  float s = 0.f;
  for (int i = threadIdx.x; i < NBLK; i += 256) s += partials[i];
#pragma unroll
  for (int off = 32; off; off >>= 1) s += __shfl_down(s, off);
  __shared__ float ws[4];
  if ((threadIdx.x & 63) == 0) ws[threadIdx.x >> 6] = s;
  __syncthreads();
  if (threadIdx.x == 0) out[0] = ws[0] + ws[1] + ws[2] + ws[3];
}

extern "C" void kernel_launch(void* const* d_in, const int* in_sizes, int n_in,
                              void* d_out, int out_size, void* d_ws, size_t ws_size,
                              hipStream_t stream) {
  const float* F = (const float*)d_in[0];
  const int*   y = (const int*)d_in[1];
  float* out = (float*)d_out;

  uint8_t* Fb = (uint8_t*)d_ws;                               // 2 MB fp4
  float*  sq = (float*)((char*)d_ws + (size_t)NROWS * RB);
  float*  rn = sq + NROWS;
  float*  partials = rn + NROWS;

  prep_kernel<<<NROWS / 4, 256, 0, stream>>>(F, Fb, sq, rn);
  gram_kernel<<<NBLK, 256, 0, stream>>>(Fb, sq, rn, y, partials);
  reduce_kernel<<<1, 256, 0, stream>>>(partials, out);
}

// Round 19
// 36.317 us; speedup vs baseline: 1.1420x; 1.1420x over previous
//
#include <hip/hip_runtime.h>
#include <stdint.h>

typedef __attribute__((ext_vector_type(4)))  int   i32x4;
typedef __attribute__((ext_vector_type(8)))  int   i32x8;
typedef __attribute__((ext_vector_type(16))) float f32x16;

#define NROWS 4096
#define RB    512      // bytes per fp4 row (1024 elems * 0.5B)
#define NKT   16       // K-tiles of 32 bytes (64 elements)
#define NB    32       // 128-row panels
#define NBLK  528      // NB*(NB+1)/2 triangular 128x128 tiles
#define COS_EPS 1e-8f
#define SCL   0x7F7F7F7F   // E8M0 = 127 -> scale 1.0
#define FP4   4            // f8f6f4 format code E2M1

__device__ __forceinline__ void gload16(const uint8_t* g, uint8_t* l) {
  __builtin_amdgcn_global_load_lds(
      (const __attribute__((address_space(1))) uint32_t*)g,
      (__attribute__((address_space(3))) uint32_t*)l, 16, 0, 0);
}

__device__ __forceinline__ i32x8 ext8(i32x4 lo) {
  i32x8 r;
  r[0] = lo[0]; r[1] = lo[1]; r[2] = lo[2]; r[3] = lo[3];
  r[4] = 0; r[5] = 0; r[6] = 0; r[7] = 0;
  return r;
}

// nearest e2m1 code for |x| (codes 0..7 -> {0,.5,1,1.5,2,3,4,6})
__device__ __forceinline__ uint32_t fp4q(float x) {
  const float a = fabsf(x);
  uint32_t c;
  if      (a < 0.25f) c = 0;
  else if (a < 0.75f) c = 1;
  else if (a < 1.25f) c = 2;
  else if (a < 1.75f) c = 3;
  else if (a < 2.5f)  c = 4;
  else if (a < 3.5f)  c = 5;
  else if (a < 5.0f)  c = 6;
  else                c = 7;
  return c | (x < 0.f ? 8u : 0u);
}

// ---------------- prep: sq, 1/norm, fp4 e2m1 copy, zero out ----------------
extern "C" __global__ void __launch_bounds__(256) prep_kernel(
    const float* __restrict__ F, uint8_t* __restrict__ Fb,
    float* __restrict__ sq, float* __restrict__ rn, float* __restrict__ out) {
  if (blockIdx.x == 0 && threadIdx.x == 0) out[0] = 0.f;   // atomic target
  const int row  = blockIdx.x * 4 + (threadIdx.x >> 6);
  const int lane = threadIdx.x & 63;
  const float4* src = (const float4*)(F + (size_t)row * 1024 + lane * 16);
  float4 v[4];
#pragma unroll
  for (int i = 0; i < 4; ++i) v[i] = src[i];
  float s = 0.f;
#pragma unroll
  for (int i = 0; i < 4; ++i)
    s += v[i].x * v[i].x + v[i].y * v[i].y + v[i].z * v[i].z + v[i].w * v[i].w;
  uint32_t b[2] = {0, 0};
#pragma unroll
  for (int i = 0; i < 4; ++i) {
    const uint32_t n0 = fp4q(v[i].x), n1 = fp4q(v[i].y);
    const uint32_t n2 = fp4q(v[i].z), n3 = fp4q(v[i].w);
    const uint32_t byte2 = (n0 | (n1 << 4)) | ((n2 | (n3 << 4)) << 8);
    b[i >> 1] |= byte2 << ((i & 1) * 16);
  }
  *(uint2*)(Fb + (size_t)row * RB + lane * 8) = make_uint2(b[0], b[1]);
#pragma unroll
  for (int off = 32; off; off >>= 1) s += __shfl_down(s, off);
  if (lane == 0) {
    sq[row] = s;
    rn[row] = 1.0f / fmaxf(sqrtf(s), COS_EPS);
  }
}

// ---------------- fused gram: FP4, triangular 128x128, 4-deep prefetch -----
// R17-verified core + 4-slot ring staging kt+3 (2 iterations of load slack;
// steady-state wait vmcnt(4), never drains) + fused atomic final reduce.
// 528 blocks, 4 waves (2Mx2N), wave = 64x64 out. Frag-major LDS: every
// ds_read_b128 is a contiguous 1 KB wave read (0 conflicts).
extern "C" __global__ void __launch_bounds__(256, 3) gram_kernel(
    const uint8_t* __restrict__ Fb, const float* __restrict__ sq,
    const float* __restrict__ rn, const int* __restrict__ y,
    float* __restrict__ out) {
  __shared__ __align__(16) uint8_t lds[4][8192];   // [slot][A 4KB | B 4KB]
  __shared__ float wsum[4];

  // XCD-chunked bijection (528 = 8*66) + triangular staircase decode
  int s = (int)(blockIdx.x & 7) * 66 + (int)(blockIdx.x >> 3);
  int bi = 0, rem0 = s;
  while (rem0 >= NB - bi) { rem0 -= NB - bi; ++bi; }
  const int bj = bi + rem0;
  const bool diag = (bi == bj);

  const int tid  = threadIdx.x;
  const int lane = tid & 63;
  const int wid  = tid >> 6;
  const int wr   = wid >> 1;      // 0..1 : 64-row group
  const int wc   = wid & 1;       // 0..1 : 64-col group
  const int kg   = lane >> 5;
  const int r32  = lane & 31;

  // staging: thread tid stages A granule tid and B granule tid per K-tile.
  // granule (f = tid>>6, l = tid&63) = row f*32+(l&31), K-bytes (l>>5)*16.
  const int srow = ((tid >> 6) << 5) + (tid & 31);     // 0..127
  const int scol = ((tid >> 5) & 1) * 16;
  const uint8_t* gA = Fb + (size_t)(bi * 128 + srow) * RB + scol;
  const uint8_t* gB = Fb + (size_t)(bj * 128 + srow) * RB + scol;
  uint8_t* ldsT = &lds[0][0] + tid * 16;

  // fragment read offsets: frag-major, lane*16 within each 1KB frag
  const int offA0 = (wr * 2 + 0) * 1024 + lane * 16;
  const int offA1 = (wr * 2 + 1) * 1024 + lane * 16;
  const int offB0 = 4096 + (wc * 2 + 0) * 1024 + lane * 16;
  const int offB1 = 4096 + (wc * 2 + 1) * 1024 + lane * 16;

  f32x16 acc[2][2] = {};

#define STAGE(kt2) do {                                                     \
    const int _sl = (kt2) & 3;                                              \
    gload16(gA + (kt2) * 32, ldsT + _sl * 8192);                            \
    gload16(gB + (kt2) * 32, ldsT + _sl * 8192 + 4096);                     \
  } while (0)

  // prologue: K-tiles 0,1,2 in flight (6 loads); wait tile 0 (leave 4)
  STAGE(0); STAGE(1); STAGE(2);
  asm volatile("s_waitcnt vmcnt(4)");
  __builtin_amdgcn_s_barrier();
  __builtin_amdgcn_sched_barrier(0);

#pragma unroll 1
  for (int kt = 0; kt < NKT; ++kt) {
    const uint8_t* sl = &lds[0][0] + (kt & 3) * 8192;

    const i32x8 A0 = ext8(*(const i32x4*)(sl + offA0));
    const i32x8 A1 = ext8(*(const i32x4*)(sl + offA1));
    const i32x8 B0 = ext8(*(const i32x4*)(sl + offB0));
    const i32x8 B1 = ext8(*(const i32x4*)(sl + offB1));

    if (kt + 3 < NKT) STAGE(kt + 3);     // writes slot (kt-1)&3: readers done

    __builtin_amdgcn_s_setprio(1);
    acc[0][0] = __builtin_amdgcn_mfma_scale_f32_32x32x64_f8f6f4(
        A0, B0, acc[0][0], FP4, FP4, 0, SCL, 0, SCL);
    acc[0][1] = __builtin_amdgcn_mfma_scale_f32_32x32x64_f8f6f4(
        A0, B1, acc[0][1], FP4, FP4, 0, SCL, 0, SCL);
    acc[1][0] = __builtin_amdgcn_mfma_scale_f32_32x32x64_f8f6f4(
        A1, B0, acc[1][0], FP4, FP4, 0, SCL, 0, SCL);
    acc[1][1] = __builtin_amdgcn_mfma_scale_f32_32x32x64_f8f6f4(
        A1, B1, acc[1][1], FP4, FP4, 0, SCL, 0, SCL);
    __builtin_amdgcn_s_setprio(0);

    // counted wait: tile kt+1 must have landed before next iteration reads it
    if (kt + 4 <= NKT)      asm volatile("s_waitcnt vmcnt(4)");
    else if (kt == NKT - 3) asm volatile("s_waitcnt vmcnt(2)");
    else if (kt == NKT - 2) asm volatile("s_waitcnt vmcnt(0)");
    if (kt < NKT - 1) {
      __builtin_amdgcn_s_barrier();
      __builtin_amdgcn_sched_barrier(0);   // next-iter ds_reads stay below
    }
  }

#undef STAGE

  // ---------- epilogue: triangle weights (32x32 C/D layout) ----------
  float sqc[2], rnc[2];
  int   yc[2];
#pragma unroll
  for (int nb = 0; nb < 2; ++nb) {
    const int gj = bj * 128 + wc * 64 + nb * 32 + r32;
    sqc[nb] = sq[gj]; rnc[nb] = rn[gj]; yc[nb] = y[gj];
  }
  float lsum = 0.f;
#pragma unroll
  for (int mt = 0; mt < 2; ++mt) {
#pragma unroll
    for (int e = 0; e < 16; ++e) {
      const int gi = bi * 128 + wr * 64 + mt * 32 + (e & 3) + 8 * (e >> 2) + 4 * kg;
      const float sqi = sq[gi], rni = rn[gi];
      const int yi = y[gi];
#pragma unroll
      for (int nb = 0; nb < 2; ++nb) {
        const int gj = bj * 128 + wc * 64 + nb * 32 + r32;
        const float g  = acc[mt][nb][e];
        const float d2 = sqi + sqc[nb] - 2.0f * g;
        const float dist = d2 > 0.f ? sqrtf(d2) : 0.f;
        const float sim  = g * rni * rnc[nb];
        const float sgn  = (yi == yc[nb]) ? 1.0f : -1.0f;
        float wgt;
        if (diag) wgt = (gj > gi) ? 2.0f : ((gj == gi) ? 1.0f : 0.0f);
        else      wgt = 2.0f;
        lsum += wgt * sgn * (dist - sim);
      }
    }
  }
#pragma unroll
  for (int off = 32; off; off >>= 1) lsum += __shfl_down(lsum, off);
  if (lane == 0) wsum[wid] = lsum;
  __syncthreads();
  if (tid == 0)
    atomicAdd(out, wsum[0] + wsum[1] + wsum[2] + wsum[3]);
}

extern "C" void kernel_launch(void* const* d_in, const int* in_sizes, int n_in,
                              void* d_out, int out_size, void* d_ws, size_t ws_size,
                              hipStream_t stream) {
  const float* F = (const float*)d_in[0];
  const int*   y = (const int*)d_in[1];
  float* out = (float*)d_out;

  uint8_t* Fb = (uint8_t*)d_ws;                               // 2 MB fp4
  float*  sq = (float*)((char*)d_ws + (size_t)NROWS * RB);
  float*  rn = sq + NROWS;

  prep_kernel<<<NROWS / 4, 256, 0, stream>>>(F, Fb, sq, rn, out);
  gram_kernel<<<NBLK, 256, 0, stream>>>(Fb, sq, rn, y, out);
}